// Round 10
// baseline (296.314 us; speedup 1.0000x reference)
//
#include <hip/hip_runtime.h>
#include <hip/hip_bf16.h>

typedef unsigned short ushort_t;
typedef unsigned int uint32;
typedef __attribute__((ext_vector_type(8))) short short8;
typedef __attribute__((ext_vector_type(4))) float floatx4;

#define DEV __device__ __forceinline__

#if defined(__has_builtin)
#if __has_builtin(__builtin_amdgcn_sdot4)
#define HAS_SDOT 1
#endif
#endif
#ifndef HAS_SDOT
#define HAS_SDOT 0
#endif

DEV float b2f(ushort_t u) { return __uint_as_float(((uint32)u) << 16); }
DEV ushort_t f2b(float f) {
  __hip_bfloat16 h = __float2bfloat16(f);
  return __builtin_bit_cast(unsigned short, h);
}
DEV void unpack8(const uint4& u, float* f) {
  f[0] = __uint_as_float(u.x << 16); f[1] = __uint_as_float(u.x & 0xffff0000u);
  f[2] = __uint_as_float(u.y << 16); f[3] = __uint_as_float(u.y & 0xffff0000u);
  f[4] = __uint_as_float(u.z << 16); f[5] = __uint_as_float(u.z & 0xffff0000u);
  f[6] = __uint_as_float(u.w << 16); f[7] = __uint_as_float(u.w & 0xffff0000u);
}
DEV void unpack_i8x8(uint2 u, float* f) {
  f[0] = (float)((int)(u.x << 24) >> 24);
  f[1] = (float)((int)(u.x << 16) >> 24);
  f[2] = (float)((int)(u.x << 8) >> 24);
  f[3] = (float)((int)u.x >> 24);
  f[4] = (float)((int)(u.y << 24) >> 24);
  f[5] = (float)((int)(u.y << 16) >> 24);
  f[6] = (float)((int)(u.y << 8) >> 24);
  f[7] = (float)((int)u.y >> 24);
}

// async global->LDS, 16B per lane; LDS dest = base + lane*16 (wave-uniform base)
#define GLOAD_LDS(gp, lp) \
  __builtin_amdgcn_global_load_lds((const __attribute__((address_space(1))) uint32*)(gp), \
                                   (__attribute__((address_space(3))) uint32*)(lp), 16, 0, 0)

// KV8 row (interleaved): 64 chunks of 16B; chunk l = {K dims 8l..8l+7 (8B int8),
// V dims 8l..8l+7 (8B int8)}, then {ks,vs} float2 x 8 heads = 1088 B = 17 lines.
#define KVROW 1088

// bijective XCD remap (nwg % 8 != 0 safe): contiguous swz chunk per XCD
DEV int xcd_swz(int wg, int nwg) {
  int q = nwg >> 3, r = nwg & 7;
  int xcd = wg & 7, idx = wg >> 3;
  return (xcd < r ? xcd * (q + 1) : r * (q + 1) + (xcd - r) * q) + idx;
}

// ---------------------------------------------------------------------------
// k_prep: fused prep pipeline (r9, kept). Block roles by blockIdx.x range:
//   [0,1024)        weight transpose; [1024,1032) biases (+flag);
//   [1032,oRp)      x -> bf16; [oRp,oAb) CSR rp; [oAb,...) att_bias -> f32.
// Dtype detection done INLINE per block (8KB of x, L2-hot).
// ---------------------------------------------------------------------------
__global__ __launch_bounds__(256) void k_prep(
    const void* __restrict__ x,
    const void* __restrict__ Wq, const void* __restrict__ Wk,
    const void* __restrict__ Wv, const void* __restrict__ Wo,
    ushort_t* __restrict__ WT4,
    const void* __restrict__ bq, const void* __restrict__ bk,
    const void* __restrict__ bv, const void* __restrict__ bo,
    float* __restrict__ biasf, ushort_t* __restrict__ xb,
    const void* __restrict__ ab, float* __restrict__ ABc,
    const int* __restrict__ rows, int* __restrict__ rp, int* __restrict__ flag,
    int E, int Nn, int n8, int n4, int abEarly,
    int oRp, int oAb) {
  __shared__ int red[256];
  __shared__ ushort_t t[32][33];
  int b = blockIdx.x;
  int tid = threadIdx.x;

  if (b >= oRp && b < oAb) {           // ---- build_rp (no detect needed)
    int i = (b - oRp) * 256 + tid;
    if (i > Nn) return;
    int lo = 0, hi = E;
    while (lo < hi) {
      int mid = (lo + hi) >> 1;
      if (rows[mid] < i) lo = mid + 1; else hi = mid;
    }
    rp[i] = lo;
    return;
  }

  // ---- inline dtype detect (block-uniform result)
  const ushort_t* xs = (const ushort_t*)x;
  int wild = 0;
  for (int i = tid; i < 4096; i += 256) {
    uint32 e = (xs[i] >> 7) & 0xFFu;
    if (e < 100u || e > 140u) wild++;
  }
  red[tid] = wild;
  __syncthreads();
  for (int s = 128; s > 0; s >>= 1) {
    if (tid < s) red[tid] += red[tid + s];
    __syncthreads();
  }
  int isf32 = red[0] > 400;

  if (b < 1024) {                      // ---- weight transpose
    int z = b >> 8, rem = b & 255;
    int by = rem >> 4, bx = rem & 15;
    int tx = tid & 31, ty = tid >> 5;  // 32 x 8
    const void* src = (z == 0) ? Wq : (z == 1) ? Wk : (z == 2) ? Wv : Wo;
    ushort_t* dst = WT4 + (size_t)z * 512 * 512;
#pragma unroll
    for (int i = 0; i < 4; i++) {
      size_t idx = (size_t)(by * 32 + ty + 8 * i) * 512 + bx * 32 + tx;
      ushort_t v = isf32 ? f2b(((const float*)src)[idx]) : ((const ushort_t*)src)[idx];
      t[ty + 8 * i][tx] = v;
    }
    __syncthreads();
#pragma unroll
    for (int i = 0; i < 4; i++)
      dst[(size_t)(bx * 32 + ty + 8 * i) * 512 + by * 32 + tx] = t[tx][ty + 8 * i];
  } else if (b < 1032) {               // ---- biases (+ flag write)
    if (b == 1024 && tid == 0) flag[0] = isf32;
    int i = (b - 1024) * 256 + tid;
    if (i >= 2048) return;
    int z = i >> 9, j = i & 511;
    const void* bb = (z == 0) ? bq : (z == 1) ? bk : (z == 2) ? bv : bo;
    biasf[i] = isf32 ? ((const float*)bb)[j] : b2f(((const ushort_t*)bb)[j]);
  } else if (b < oRp) {                // ---- x -> bf16 plane
    int i = (b - 1032) * 256 + tid;
    if (i >= n8) return;
    if (isf32) {
      const float* xf = (const float*)x + (size_t)i * 8;
      float4 f0 = ((const float4*)xf)[0];
      float4 f1 = ((const float4*)xf)[1];
      uint4 o;
      o.x = (uint32)f2b(f0.x) | ((uint32)f2b(f0.y) << 16);
      o.y = (uint32)f2b(f0.z) | ((uint32)f2b(f0.w) << 16);
      o.z = (uint32)f2b(f1.x) | ((uint32)f2b(f1.y) << 16);
      o.w = (uint32)f2b(f1.z) | ((uint32)f2b(f1.w) << 16);
      ((uint4*)xb)[i] = o;
    } else {
      ((uint4*)xb)[i] = ((const uint4*)x)[i];
    }
  } else {                             // ---- att_bias -> f32 (early path)
    if (!abEarly || isf32) return;     // f32 input: k_edge reads ab directly
    int i = (b - oAb) * 256 + tid;
    if (i >= n4) return;
    uint2 u = ((const uint2*)ab)[i];
    float4 o;
    o.x = __uint_as_float(u.x << 16);
    o.y = __uint_as_float(u.x & 0xffff0000u);
    o.z = __uint_as_float(u.y << 16);
    o.w = __uint_as_float(u.y & 0xffff0000u);
    ((float4*)ABc)[i] = o;
  }
}

// late convab (fallback when ABc must alias xb: runs after k_gemm_qkv)
__global__ __launch_bounds__(256) void k_convab(
    const void* __restrict__ ab, float* __restrict__ ABc, int n4,
    const int* __restrict__ flagp) {
  if (*flagp) return;
  int i = blockIdx.x * 256 + threadIdx.x;
  if (i >= n4) return;
  uint2 u = ((const uint2*)ab)[i];
  float4 o;
  o.x = __uint_as_float(u.x << 16);
  o.y = __uint_as_float(u.x & 0xffff0000u);
  o.z = __uint_as_float(u.y << 16);
  o.w = __uint_as_float(u.y & 0xffff0000u);
  ((float4*)ABc)[i] = o;
}

// ---------------------------------------------------------------------------
// GEMM C[M,512] = A[M,512] @ B[512,512] (+bias)*scale, BT given, 256x256 tile.
// 8 waves (2x4), per-wave output 128x64 (acc 8x4), BK=64 -> 64 MFMA per wave
// per barrier-pair, 8 K-tiles, 128 KiB double-buffered LDS, counted vmcnt(8),
// setprio around MFMA clusters. (r6 version -- best measured, qkv < 59.6us.)
// LDS swizzle (both-sides): logical chunk c (16B) at row r -> phys c^(r&7);
// staged via pre-swizzled global source (gload_lds dest stays linear),
// read with phys = (kk*4+quad)^(lm&7).
// Output modes: 0 = bf16 (ldc), 1 = f32 (ldc), 3 = int8 K-plane into KV8,
// 4 = int8 V-plane. (r8's biased-uint8 V REVERTED: cut VALU but +6.5us.)
// KV8 byte placement: dim d -> byte 16*(d>>3) + 8*vslot + (d&7).
// ---------------------------------------------------------------------------
DEV void gemm_body256(const ushort_t* __restrict__ A, const ushort_t* __restrict__ BT,
                      const float* __restrict__ bias, void* C,
                      int M, int ldc, float scale, int row0, int by, int mode) {
  __shared__ ushort_t Ab[2][256 * 64];   // 64 KiB
  __shared__ ushort_t Bb[2][256 * 64];   // 64 KiB
  int tid = threadIdx.x;                 // 0..511
  int w = tid >> 6, lane = tid & 63;
  int lm = lane & 15, quad = lane >> 4;
  int wr = w >> 2, wc = w & 3;

  // drain any prior vmem (e.g. caller's flag load) so vmcnt counting is exact
  asm volatile("s_waitcnt vmcnt(0)" ::: "memory");

  // staging: issue i covers local rows i*64..i*64+63; this thread owns local
  // row i*64 + w*8 + (lane>>3), dest chunk lane&7. Source logical chunk =
  // (lane&7)^(row&7) with row&7 == lane>>3  -> pre-swizzled global offset.
  int clog8 = ((lane & 7) ^ (lane >> 3)) * 8;
  int arow[4], brow[4];
#pragma unroll
  for (int i = 0; i < 4; i++) {
    int r = row0 + i * 64 + w * 8 + (lane >> 3);
    arow[i] = (r < M) ? r : (M - 1);
    brow[i] = by * 256 + i * 64 + w * 8 + (lane >> 3);
  }

  floatx4 acc[8][4];
#pragma unroll
  for (int i = 0; i < 8; i++)
#pragma unroll
    for (int j = 0; j < 4; j++)
#pragma unroll
      for (int r = 0; r < 4; r++) acc[i][j][r] = 0.f;

  auto stage = [&](int buf, int kt) {
    int k0 = kt * 64 + clog8;
#pragma unroll
    for (int i = 0; i < 4; i++)
      GLOAD_LDS(A + (size_t)arow[i] * 512 + k0, &Ab[buf][(i * 64 + w * 8) * 64]);
#pragma unroll
    for (int i = 0; i < 4; i++)
      GLOAD_LDS(BT + (size_t)brow[i] * 512 + k0, &Bb[buf][(i * 64 + w * 8) * 64]);
  };

  // read-side: frag row bases (wr*128, mt*16, wc*64, nt*16) are 0 mod 8, so
  // row&7 == lm&7 for every fragment row -> one phys offset per kk.
  int ph0 = ((0 + quad) ^ (lm & 7)) * 8;
  int ph1 = ((4 + quad) ^ (lm & 7)) * 8;

  auto compute = [&](int cur) {
#pragma unroll
    for (int kk = 0; kk < 2; kk++) {
      int ph = kk ? ph1 : ph0;
      const ushort_t* pa = &Ab[cur][(wr * 128 + lm) * 64] + ph;
      const ushort_t* pb = &Bb[cur][(wc * 64 + lm) * 64] + ph;
      short8 af[8], bf[4];
#pragma unroll
      for (int nt = 0; nt < 4; nt++) bf[nt] = *(const short8*)(pb + nt * 16 * 64);
#pragma unroll
      for (int mt = 0; mt < 8; mt++) af[mt] = *(const short8*)(pa + mt * 16 * 64);
      __builtin_amdgcn_s_setprio(1);
#pragma unroll
      for (int mt = 0; mt < 8; mt++)
#pragma unroll
        for (int nt = 0; nt < 4; nt++)
          acc[mt][nt] = __builtin_amdgcn_mfma_f32_16x16x32_bf16(af[mt], bf[nt], acc[mt][nt], 0, 0, 0);
      __builtin_amdgcn_s_setprio(0);
    }
  };

  stage(0, 0);
#pragma unroll 1
  for (int kt = 0; kt < 8; ++kt) {
    int cur = kt & 1;
    if (kt < 7) {
      stage(cur ^ 1, kt + 1);                       // 8 more loads in flight
      asm volatile("s_waitcnt vmcnt(8)" ::: "memory");  // drain tile kt only
    } else {
      asm volatile("s_waitcnt vmcnt(0)" ::: "memory");
    }
    __builtin_amdgcn_s_barrier();                   // buf[cur] ready for all
    compute(cur);
    if (kt < 7) {
      asm volatile("s_waitcnt lgkmcnt(0)" ::: "memory");
      __builtin_amdgcn_s_barrier();                 // reads done before overwrite
    }
  }

  // epilogue: C/D layout col=lane&15, row=quad*4+reg
  int colB = by * 256 + wc * 64 + lm;
  float bv4[4];
#pragma unroll
  for (int nt = 0; nt < 4; nt++) bv4[nt] = bias[colB + nt * 16];

  if (mode <= 1) {
#pragma unroll
    for (int mt = 0; mt < 8; mt++) {
      int rg0 = row0 + wr * 128 + mt * 16 + quad * 4;
#pragma unroll
      for (int nt = 0; nt < 4; nt++) {
#pragma unroll
        for (int r = 0; r < 4; r++) {
          int rg = rg0 + r;
          if (rg < M) {
            float val = (acc[mt][nt][r] + bv4[nt]) * scale;
            size_t off = (size_t)rg * ldc + colB + nt * 16;
            if (mode == 1) ((float*)C)[off] = val;
            else           ((ushort_t*)C)[off] = f2b(val);
          }
        }
      }
    }
  } else {
    int vslot = (mode == 4);
    int head = (by * 256 + wc * 64) >> 6;   // 0..7, one 64-col head per wave
#pragma unroll
    for (int mt = 0; mt < 8; mt++) {
#pragma unroll
      for (int r = 0; r < 4; r++) {
        int rg = row0 + wr * 128 + mt * 16 + quad * 4 + r;
        float v0 = acc[mt][0][r] + bv4[0];
        float v1 = acc[mt][1][r] + bv4[1];
        float v2 = acc[mt][2][r] + bv4[2];
        float v3 = acc[mt][3][r] + bv4[3];
        float am = fmaxf(fmaxf(fabsf(v0), fabsf(v1)), fmaxf(fabsf(v2), fabsf(v3)));
        am = fmaxf(am, __shfl_xor(am, 1));
        am = fmaxf(am, __shfl_xor(am, 2));
        am = fmaxf(am, __shfl_xor(am, 4));
        am = fmaxf(am, __shfl_xor(am, 8));
        am = fmaxf(am, 1e-20f);
        float inv8 = 127.0f / am;
        float sc8 = am * (1.0f / 127.0f);
        if (rg < M) {
          unsigned char* Crow = (unsigned char*)C + (size_t)rg * KVROW;
          // dim d = head*64 + nt*16 + lm -> byte 16*(d>>3) + 8*vslot + (d&7)
          unsigned char* bp = Crow + head * 128 + (lm >> 3) * 16 + 8 * vslot + (lm & 7);
          bp[ 0] = (unsigned char)(signed char)(int)rintf(v0 * inv8);
          bp[32] = (unsigned char)(signed char)(int)rintf(v1 * inv8);
          bp[64] = (unsigned char)(signed char)(int)rintf(v2 * inv8);
          bp[96] = (unsigned char)(signed char)(int)rintf(v3 * inv8);
          if (lm == 0)
            *(float*)(Crow + 1024 + head * 8 + vslot * 4) = sc8;
        }
      }
    }
  }
}

// 1D grid rt*6, XCD-swizzled: the 6 (by,z) blocks of a 256-row panel land in
// one XCD chunk -> A panel fetched once per XCD L2 (r5: FETCH 127->17.6 MB).
// z=0 -> Q plane bf16 (ldc 512, scale 1/8); z=1 -> K int8; z=2 -> V int8.
__global__ __launch_bounds__(512, 2) void k_gemm_qkv(
    const ushort_t* __restrict__ xb, const ushort_t* __restrict__ WT4,
    const float* __restrict__ biasf, ushort_t* Qp, unsigned char* KV8, int M) {
  int swz = xcd_swz(blockIdx.x, gridDim.x);
  int row = swz / 6;
  int sub = swz - row * 6;
  int by = sub & 1, z = sub >> 1;
  const ushort_t* BT = WT4 + (size_t)z * 512 * 512;
  const float* bias = biasf + (size_t)z * 512;
  if (z == 0)
    gemm_body256(xb, BT, bias, Qp, M, 512, 0.125f, row * 256, by, 0);
  else
    gemm_body256(xb, BT, bias, KV8, M, 0, 1.0f, row * 256, by, z == 1 ? 3 : 4);
}

// 1D grid rt*2, same XCD chunking
__global__ __launch_bounds__(512, 2) void k_gemm_out(
    const ushort_t* __restrict__ y, const ushort_t* __restrict__ WT4,
    const float* __restrict__ biasf, void* out, int M,
    const int* __restrict__ flagp) {
  int mode = *flagp;
  int swz = xcd_swz(blockIdx.x, gridDim.x);
  int row = swz >> 1, by = swz & 1;
  gemm_body256(y, WT4 + (size_t)3 * 512 * 512, biasf + 3 * 512, out, M, 512, 1.0f,
               row * 256, by, mode);
}

// ---------------------------------------------------------------------------
// Per-node attention + V aggregation. r10: ONE BLOCK (4 waves) PER NODE --
// each wave handles edges t = sub (mod 4) within each 64-edge chunk, cutting
// the per-wave serial chain 16 -> ~4 edges (= ring depth, fully overlapped
// issue) and 4x-ing independent gather chains (80k waves). Partials (acc, s
// -- all linear) combined via LDS; wave 0 finalizes. Rationale: r9 counters
// show ~1500 cy/edge wall per wave vs ~100 cy VALU -- latency-bound serial
// chain, and ring depth is HARD-CAPPED at 4 (depth 8 spilled twice: r2
// WRITE 388MB, r7 301MB). More chains is the remaining concurrency axis.
// De-chained gather (readlane bcast of coalesced cols load); K int8 + Q int8
// per (node,head) -> 2x v_dot4_i32_i8; V signed int8 (r8 bias trick hurt).
// No max-subtraction (logits O(+-10), clamp 80). Writes y bf16 over Q plane.
// Grid = M blocks exactly (no early return -> __syncthreads uniform).
// ---------------------------------------------------------------------------
__global__ __launch_bounds__(256) void k_edge(
    ushort_t* Qy, const unsigned char* __restrict__ KV8,
    const void* __restrict__ ab, const float* __restrict__ ABc,
    const int* __restrict__ cols, const int* __restrict__ rp, int Nn,
    const int* __restrict__ flagp) {
  __shared__ float part[3][64][10];    // waves 1..3: acc[8], s (stride 10)
  int node = blockIdx.x;
  int w = threadIdx.x >> 6;            // wave 0..3; edge subset t%4 == w
  int lane = threadIdx.x & 63;
  int h8 = lane >> 3;
  const float* abf32 = (*flagp) ? (const float*)ab : ABc;

  uint4 qu = ((const uint4*)(Qy + (size_t)node * 512))[lane];
  float qf[8];
  unpack8(qu, qf);

#if HAS_SDOT
  // quantize Q per (node, head): head = one 8-lane group x 8 dims/lane
  float qa = 0.f;
#pragma unroll
  for (int j = 0; j < 8; j++) qa = fmaxf(qa, fabsf(qf[j]));
  qa = fmaxf(qa, __shfl_xor(qa, 1));
  qa = fmaxf(qa, __shfl_xor(qa, 2));
  qa = fmaxf(qa, __shfl_xor(qa, 4));
  qa = fmaxf(qa, 1e-20f);
  float qs = qa * (1.0f / 127.0f);
  float qinv = 127.0f / qa;
  int qp0 = 0, qp1 = 0;
#pragma unroll
  for (int j = 0; j < 4; j++) qp0 |= (((int)rintf(qf[j] * qinv)) & 0xFF) << (8 * j);
#pragma unroll
  for (int j = 4; j < 8; j++) qp1 |= (((int)rintf(qf[j] * qinv)) & 0xFF) << (8 * (j - 4));
#endif

  int e0 = rp[node], e1 = rp[node + 1];
  int cnt = e1 - e0;

  float s0 = 0.f, s1 = 0.f;
  float acc0[8], acc1[8];
#pragma unroll
  for (int j = 0; j < 8; j++) { acc0[j] = 0.f; acc1[j] = 0.f; }

  uint4 kvb[4];
  float2 scb[4];
  float abv[4];

  // chunked over 64 edges: one coalesced cols load per chunk, readlane bcast;
  // this wave consumes t = w + 4*slot + 16*it within the chunk.
  for (int base = 0; base < cnt; base += 64) {
    int rem = cnt - base; if (rem > 64) rem = 64;
    int li = (lane < rem) ? lane : (rem - 1);
    int myc = cols[e0 + base + li];
    const float* abp = abf32 + (size_t)(e0 + base) * 8 + h8;

    auto pref = [&](int t, int slot) {
      int valid = t < rem;
      int c = __builtin_amdgcn_readlane(myc, valid ? t : 0);
      const unsigned char* kvrow = KV8 + (size_t)c * KVROW;
      kvb[slot] = *(const uint4*)(kvrow + lane * 16);
      scb[slot] = *(const float2*)(kvrow + 1024 + h8 * 8);
      float a = abp[(valid ? t : 0) * 8];
      abv[slot] = valid ? a : -1e30f;    // exp(-1e30) = 0 -> no contribution
    };
    auto consume = [&](int slot, float* acc, float& s) {
#if HAS_SDOT
      int di = __builtin_amdgcn_sdot4(qp0, (int)kvb[slot].x, 0, false);
      di = __builtin_amdgcn_sdot4(qp1, (int)kvb[slot].y, di, false);
      di += __shfl_xor(di, 1);
      di += __shfl_xor(di, 2);
      di += __shfl_xor(di, 4);
      float logit = fminf(fmaf((float)di * qs, scb[slot].x, abv[slot]), 80.f);
#else
      float kf[8];
      uint2 ku; ku.x = kvb[slot].x; ku.y = kvb[slot].y;
      unpack_i8x8(ku, kf);
      float d = 0.f;
#pragma unroll
      for (int j = 0; j < 8; j++) d = fmaf(qf[j], kf[j], d);
      d += __shfl_xor(d, 1);
      d += __shfl_xor(d, 2);
      d += __shfl_xor(d, 4);
      float logit = fminf(fmaf(d, scb[slot].x, abv[slot]), 80.f);
#endif
      float pw = __expf(logit);
      s += pw;
      float pwv = pw * scb[slot].y;
      float vf[8];
      uint2 vu; vu.x = kvb[slot].z; vu.y = kvb[slot].w;
      unpack_i8x8(vu, vf);
#pragma unroll
      for (int j = 0; j < 8; j++) acc[j] = fmaf(pwv, vf[j], acc[j]);
    };

    pref(w + 0, 0); pref(w + 4, 1); pref(w + 8, 2); pref(w + 12, 3);
    int iters = (rem + 15) >> 4;      // covers t = w + 4*slot + 16*it < rem
    for (int it = 0; it < iters; ++it) {
      int nt = w + 16 * (it + 1);
      consume(0, acc0, s0); pref(nt + 0, 0);
      consume(1, acc1, s1); pref(nt + 4, 1);
      consume(2, acc0, s0); pref(nt + 8, 2);
      consume(3, acc1, s1); pref(nt + 12, 3);
    }
  }

  // combine partials across the 4 waves (all linear): waves 1-3 -> LDS
  if (w > 0) {
#pragma unroll
    for (int j = 0; j < 8; j++) part[w - 1][lane][j] = acc0[j] + acc1[j];
    part[w - 1][lane][8] = s0 + s1;
  }
  __syncthreads();
  if (w == 0) {
    float accT[8];
    float s = s0 + s1;
#pragma unroll
    for (int j = 0; j < 8; j++) accT[j] = acc0[j] + acc1[j];
#pragma unroll
    for (int p = 0; p < 3; p++) {
#pragma unroll
      for (int j = 0; j < 8; j++) accT[j] += part[p][lane][j];
      s += part[p][lane][8];
    }
    float inv = (cnt > 0 && s > 0.f) ? 1.f / s : 0.f;
    ushort_t hb[8];
#pragma unroll
    for (int j = 0; j < 8; j++) hb[j] = f2b(accT[j] * inv);
    uint4 uh;
    uh.x = (uint32)hb[0] | ((uint32)hb[1] << 16);
    uh.y = (uint32)hb[2] | ((uint32)hb[3] << 16);
    uh.z = (uint32)hb[4] | ((uint32)hb[5] << 16);
    uh.w = (uint32)hb[6] | ((uint32)hb[7] << 16);
    ((uint4*)(Qy + (size_t)node * 512))[lane] = uh;
  }
}

// ---------------------------------------------------------------------------
extern "C" void kernel_launch(void* const* d_in, const int* in_sizes, int n_in,
                              void* d_out, int out_size, void* d_ws, size_t ws_size,
                              hipStream_t stream) {
  const void* x  = d_in[0];
  const int* ei  = (const int*)d_in[1];
  const void* ab = d_in[2];
  const void* Wq = d_in[3];
  const void* bq = d_in[4];
  const void* Wk = d_in[5];
  const void* bk = d_in[6];
  const void* Wv = d_in[7];
  const void* bv = d_in[8];
  const void* Wo = d_in[9];
  const void* bo = d_in[10];

  const int D = 512;
  int M = in_sizes[0] / D;   // 20000 nodes
  int E = in_sizes[1] / 2;   // 320000 edges
  const int* rows = ei;
  const int* cols = ei + E;

  char* p = (char*)d_ws;
  size_t off = 0;
  auto carve = [&](size_t bytes) -> void* {
    off = (off + 255) & ~(size_t)255;
    void* r = p + off;
    off += bytes;
    return r;
  };
  int* flag          = (int*)carve(4);
  ushort_t* WT4      = (ushort_t*)carve((size_t)4 * 512 * 512 * 2);  //  2.00 MB
  float* biasf       = (float*)carve((size_t)4 * 512 * 4);           //  0.01 MB
  ushort_t* xb       = (ushort_t*)carve((size_t)M * 512 * 2);        // 20.48 MB
  ushort_t* Qp       = (ushort_t*)carve((size_t)M * 512 * 2);        // 20.48 MB (y aliases)
  unsigned char* KV8 = (unsigned char*)carve((size_t)M * KVROW);     // 21.76 MB
  int* rp            = (int*)carve((size_t)(M + 1) * 4);             //  0.08 MB

  // ABc: prefer its own carve (lets convab run inside k_prep). Fall back to
  // aliasing xb (then convab must run AFTER k_gemm_qkv, costing one launch).
  int n4 = E * 8 / 4;
  size_t abBytes = (size_t)E * 8 * 4;
  float* ABc;
  int abEarly;
  if (off + 256 + abBytes <= ws_size) {
    ABc = (float*)carve(abBytes);      // 10.24 MB, total ~76 MB
    abEarly = 1;
  } else {
    ABc = (float*)xb;                  // xb dead after k_gemm_qkv
    abEarly = 0;
  }

  int n8 = M * 512 / 8;
  int nCx = (n8 + 255) / 256;
  int nRp = (M + 1 + 255) / 256;
  int nAb = (n4 + 255) / 256;
  int oRp = 1032 + nCx;
  int oAb = oRp + nRp;
  int oEnd = oAb + nAb;

  k_prep<<<oEnd, 256, 0, stream>>>(x, Wq, Wk, Wv, Wo, WT4, bq, bk, bv, bo,
                                   biasf, xb, ab, ABc, rows, rp, flag,
                                   E, M, n8, n4, abEarly, oRp, oAb);

  int rt = (M + 255) / 256;
  k_gemm_qkv<<<rt * 6, 512, 0, stream>>>(xb, WT4, biasf, Qp, KV8, M);
  if (!abEarly)
    k_convab<<<nAb, 256, 0, stream>>>(ab, ABc, n4, flag);
  k_edge<<<M, 256, 0, stream>>>(Qp, KV8, ab, ABc, cols, rp, M, flag);
  k_gemm_out<<<rt * 2, 512, 0, stream>>>(Qp, WT4, biasf, d_out, M, flag);
}

// Round 11
// 259.677 us; speedup vs baseline: 1.1411x; 1.1411x over previous
//
#include <hip/hip_runtime.h>
#include <hip/hip_bf16.h>

typedef unsigned short ushort_t;
typedef unsigned int uint32;
typedef __attribute__((ext_vector_type(8))) short short8;
typedef __attribute__((ext_vector_type(4))) float floatx4;

#define DEV __device__ __forceinline__

#if defined(__has_builtin)
#if __has_builtin(__builtin_amdgcn_sdot4)
#define HAS_SDOT 1
#endif
#endif
#ifndef HAS_SDOT
#define HAS_SDOT 0
#endif

DEV float b2f(ushort_t u) { return __uint_as_float(((uint32)u) << 16); }
DEV ushort_t f2b(float f) {
  __hip_bfloat16 h = __float2bfloat16(f);
  return __builtin_bit_cast(unsigned short, h);
}
DEV void unpack8(const uint4& u, float* f) {
  f[0] = __uint_as_float(u.x << 16); f[1] = __uint_as_float(u.x & 0xffff0000u);
  f[2] = __uint_as_float(u.y << 16); f[3] = __uint_as_float(u.y & 0xffff0000u);
  f[4] = __uint_as_float(u.z << 16); f[5] = __uint_as_float(u.z & 0xffff0000u);
  f[6] = __uint_as_float(u.w << 16); f[7] = __uint_as_float(u.w & 0xffff0000u);
}
DEV void unpack_i8x8(uint2 u, float* f) {
  f[0] = (float)((int)(u.x << 24) >> 24);
  f[1] = (float)((int)(u.x << 16) >> 24);
  f[2] = (float)((int)(u.x << 8) >> 24);
  f[3] = (float)((int)u.x >> 24);
  f[4] = (float)((int)(u.y << 24) >> 24);
  f[5] = (float)((int)(u.y << 16) >> 24);
  f[6] = (float)((int)(u.y << 8) >> 24);
  f[7] = (float)((int)u.y >> 24);
}

// async global->LDS, 16B per lane; LDS dest = base + lane*16 (wave-uniform base)
#define GLOAD_LDS(gp, lp) \
  __builtin_amdgcn_global_load_lds((const __attribute__((address_space(1))) uint32*)(gp), \
                                   (__attribute__((address_space(3))) uint32*)(lp), 16, 0, 0)

// KV8 row (interleaved): 64 chunks of 16B; chunk l = {K dims 8l..8l+7 (8B int8),
// V dims 8l..8l+7 (8B int8)}, then {ks,vs} float2 x 8 heads = 1088 B = 17 lines.
#define KVROW 1088

// bijective XCD remap (nwg % 8 != 0 safe): contiguous swz chunk per XCD
DEV int xcd_swz(int wg, int nwg) {
  int q = nwg >> 3, r = nwg & 7;
  int xcd = wg & 7, idx = wg >> 3;
  return (xcd < r ? xcd * (q + 1) : r * (q + 1) + (xcd - r) * q) + idx;
}

// ---------------------------------------------------------------------------
// k_prep: fused prep pipeline (r9, kept). Block roles by blockIdx.x range:
//   [0,1024)        weight transpose; [1024,1032) biases (+flag);
//   [1032,oRp)      x -> bf16; [oRp,oAb) CSR rp; [oAb,...) att_bias -> f32.
// Dtype detection done INLINE per block (8KB of x, L2-hot).
// ---------------------------------------------------------------------------
__global__ __launch_bounds__(256) void k_prep(
    const void* __restrict__ x,
    const void* __restrict__ Wq, const void* __restrict__ Wk,
    const void* __restrict__ Wv, const void* __restrict__ Wo,
    ushort_t* __restrict__ WT4,
    const void* __restrict__ bq, const void* __restrict__ bk,
    const void* __restrict__ bv, const void* __restrict__ bo,
    float* __restrict__ biasf, ushort_t* __restrict__ xb,
    const void* __restrict__ ab, float* __restrict__ ABc,
    const int* __restrict__ rows, int* __restrict__ rp, int* __restrict__ flag,
    int E, int Nn, int n8, int n4, int abEarly,
    int oRp, int oAb) {
  __shared__ int red[256];
  __shared__ ushort_t t[32][33];
  int b = blockIdx.x;
  int tid = threadIdx.x;

  if (b >= oRp && b < oAb) {           // ---- build_rp (no detect needed)
    int i = (b - oRp) * 256 + tid;
    if (i > Nn) return;
    int lo = 0, hi = E;
    while (lo < hi) {
      int mid = (lo + hi) >> 1;
      if (rows[mid] < i) lo = mid + 1; else hi = mid;
    }
    rp[i] = lo;
    return;
  }

  // ---- inline dtype detect (block-uniform result)
  const ushort_t* xs = (const ushort_t*)x;
  int wild = 0;
  for (int i = tid; i < 4096; i += 256) {
    uint32 e = (xs[i] >> 7) & 0xFFu;
    if (e < 100u || e > 140u) wild++;
  }
  red[tid] = wild;
  __syncthreads();
  for (int s = 128; s > 0; s >>= 1) {
    if (tid < s) red[tid] += red[tid + s];
    __syncthreads();
  }
  int isf32 = red[0] > 400;

  if (b < 1024) {                      // ---- weight transpose
    int z = b >> 8, rem = b & 255;
    int by = rem >> 4, bx = rem & 15;
    int tx = tid & 31, ty = tid >> 5;  // 32 x 8
    const void* src = (z == 0) ? Wq : (z == 1) ? Wk : (z == 2) ? Wv : Wo;
    ushort_t* dst = WT4 + (size_t)z * 512 * 512;
#pragma unroll
    for (int i = 0; i < 4; i++) {
      size_t idx = (size_t)(by * 32 + ty + 8 * i) * 512 + bx * 32 + tx;
      ushort_t v = isf32 ? f2b(((const float*)src)[idx]) : ((const ushort_t*)src)[idx];
      t[ty + 8 * i][tx] = v;
    }
    __syncthreads();
#pragma unroll
    for (int i = 0; i < 4; i++)
      dst[(size_t)(bx * 32 + ty + 8 * i) * 512 + by * 32 + tx] = t[tx][ty + 8 * i];
  } else if (b < 1032) {               // ---- biases (+ flag write)
    if (b == 1024 && tid == 0) flag[0] = isf32;
    int i = (b - 1024) * 256 + tid;
    if (i >= 2048) return;
    int z = i >> 9, j = i & 511;
    const void* bb = (z == 0) ? bq : (z == 1) ? bk : (z == 2) ? bv : bo;
    biasf[i] = isf32 ? ((const float*)bb)[j] : b2f(((const ushort_t*)bb)[j]);
  } else if (b < oRp) {                // ---- x -> bf16 plane
    int i = (b - 1032) * 256 + tid;
    if (i >= n8) return;
    if (isf32) {
      const float* xf = (const float*)x + (size_t)i * 8;
      float4 f0 = ((const float4*)xf)[0];
      float4 f1 = ((const float4*)xf)[1];
      uint4 o;
      o.x = (uint32)f2b(f0.x) | ((uint32)f2b(f0.y) << 16);
      o.y = (uint32)f2b(f0.z) | ((uint32)f2b(f0.w) << 16);
      o.z = (uint32)f2b(f1.x) | ((uint32)f2b(f1.y) << 16);
      o.w = (uint32)f2b(f1.z) | ((uint32)f2b(f1.w) << 16);
      ((uint4*)xb)[i] = o;
    } else {
      ((uint4*)xb)[i] = ((const uint4*)x)[i];
    }
  } else {                             // ---- att_bias -> f32 (early path)
    if (!abEarly || isf32) return;     // f32 input: k_edge reads ab directly
    int i = (b - oAb) * 256 + tid;
    if (i >= n4) return;
    uint2 u = ((const uint2*)ab)[i];
    float4 o;
    o.x = __uint_as_float(u.x << 16);
    o.y = __uint_as_float(u.x & 0xffff0000u);
    o.z = __uint_as_float(u.y << 16);
    o.w = __uint_as_float(u.y & 0xffff0000u);
    ((float4*)ABc)[i] = o;
  }
}

// late convab (fallback when ABc must alias xb: runs after k_gemm_qkv)
__global__ __launch_bounds__(256) void k_convab(
    const void* __restrict__ ab, float* __restrict__ ABc, int n4,
    const int* __restrict__ flagp) {
  if (*flagp) return;
  int i = blockIdx.x * 256 + threadIdx.x;
  if (i >= n4) return;
  uint2 u = ((const uint2*)ab)[i];
  float4 o;
  o.x = __uint_as_float(u.x << 16);
  o.y = __uint_as_float(u.x & 0xffff0000u);
  o.z = __uint_as_float(u.y << 16);
  o.w = __uint_as_float(u.y & 0xffff0000u);
  ((float4*)ABc)[i] = o;
}

// ---------------------------------------------------------------------------
// GEMM C[M,512] = A[M,512] @ B[512,512] (+bias)*scale, BT given, 256x256 tile.
// 8 waves (2x4), per-wave output 128x64 (acc 8x4), BK=64 -> 64 MFMA per wave
// per barrier-pair, 8 K-tiles, 128 KiB double-buffered LDS, counted vmcnt(8),
// setprio around MFMA clusters. (r6 version -- best measured, qkv < 59.6us.)
// LDS swizzle (both-sides): logical chunk c (16B) at row r -> phys c^(r&7);
// staged via pre-swizzled global source (gload_lds dest stays linear),
// read with phys = (kk*4+quad)^(lm&7).
// Output modes: 0 = bf16 (ldc), 1 = f32 (ldc), 3 = int8 K-plane into KV8,
// 4 = int8 V-plane. (r8's biased-uint8 V REVERTED: cut VALU but +6.5us.)
// KV8 byte placement: dim d -> byte 16*(d>>3) + 8*vslot + (d&7).
// ---------------------------------------------------------------------------
DEV void gemm_body256(const ushort_t* __restrict__ A, const ushort_t* __restrict__ BT,
                      const float* __restrict__ bias, void* C,
                      int M, int ldc, float scale, int row0, int by, int mode) {
  __shared__ ushort_t Ab[2][256 * 64];   // 64 KiB
  __shared__ ushort_t Bb[2][256 * 64];   // 64 KiB
  int tid = threadIdx.x;                 // 0..511
  int w = tid >> 6, lane = tid & 63;
  int lm = lane & 15, quad = lane >> 4;
  int wr = w >> 2, wc = w & 3;

  // drain any prior vmem (e.g. caller's flag load) so vmcnt counting is exact
  asm volatile("s_waitcnt vmcnt(0)" ::: "memory");

  // staging: issue i covers local rows i*64..i*64+63; this thread owns local
  // row i*64 + w*8 + (lane>>3), dest chunk lane&7. Source logical chunk =
  // (lane&7)^(row&7) with row&7 == lane>>3  -> pre-swizzled global offset.
  int clog8 = ((lane & 7) ^ (lane >> 3)) * 8;
  int arow[4], brow[4];
#pragma unroll
  for (int i = 0; i < 4; i++) {
    int r = row0 + i * 64 + w * 8 + (lane >> 3);
    arow[i] = (r < M) ? r : (M - 1);
    brow[i] = by * 256 + i * 64 + w * 8 + (lane >> 3);
  }

  floatx4 acc[8][4];
#pragma unroll
  for (int i = 0; i < 8; i++)
#pragma unroll
    for (int j = 0; j < 4; j++)
#pragma unroll
      for (int r = 0; r < 4; r++) acc[i][j][r] = 0.f;

  auto stage = [&](int buf, int kt) {
    int k0 = kt * 64 + clog8;
#pragma unroll
    for (int i = 0; i < 4; i++)
      GLOAD_LDS(A + (size_t)arow[i] * 512 + k0, &Ab[buf][(i * 64 + w * 8) * 64]);
#pragma unroll
    for (int i = 0; i < 4; i++)
      GLOAD_LDS(BT + (size_t)brow[i] * 512 + k0, &Bb[buf][(i * 64 + w * 8) * 64]);
  };

  // read-side: frag row bases (wr*128, mt*16, wc*64, nt*16) are 0 mod 8, so
  // row&7 == lm&7 for every fragment row -> one phys offset per kk.
  int ph0 = ((0 + quad) ^ (lm & 7)) * 8;
  int ph1 = ((4 + quad) ^ (lm & 7)) * 8;

  auto compute = [&](int cur) {
#pragma unroll
    for (int kk = 0; kk < 2; kk++) {
      int ph = kk ? ph1 : ph0;
      const ushort_t* pa = &Ab[cur][(wr * 128 + lm) * 64] + ph;
      const ushort_t* pb = &Bb[cur][(wc * 64 + lm) * 64] + ph;
      short8 af[8], bf[4];
#pragma unroll
      for (int nt = 0; nt < 4; nt++) bf[nt] = *(const short8*)(pb + nt * 16 * 64);
#pragma unroll
      for (int mt = 0; mt < 8; mt++) af[mt] = *(const short8*)(pa + mt * 16 * 64);
      __builtin_amdgcn_s_setprio(1);
#pragma unroll
      for (int mt = 0; mt < 8; mt++)
#pragma unroll
        for (int nt = 0; nt < 4; nt++)
          acc[mt][nt] = __builtin_amdgcn_mfma_f32_16x16x32_bf16(af[mt], bf[nt], acc[mt][nt], 0, 0, 0);
      __builtin_amdgcn_s_setprio(0);
    }
  };

  stage(0, 0);
#pragma unroll 1
  for (int kt = 0; kt < 8; ++kt) {
    int cur = kt & 1;
    if (kt < 7) {
      stage(cur ^ 1, kt + 1);                       // 8 more loads in flight
      asm volatile("s_waitcnt vmcnt(8)" ::: "memory");  // drain tile kt only
    } else {
      asm volatile("s_waitcnt vmcnt(0)" ::: "memory");
    }
    __builtin_amdgcn_s_barrier();                   // buf[cur] ready for all
    compute(cur);
    if (kt < 7) {
      asm volatile("s_waitcnt lgkmcnt(0)" ::: "memory");
      __builtin_amdgcn_s_barrier();                 // reads done before overwrite
    }
  }

  // epilogue: C/D layout col=lane&15, row=quad*4+reg
  int colB = by * 256 + wc * 64 + lm;
  float bv4[4];
#pragma unroll
  for (int nt = 0; nt < 4; nt++) bv4[nt] = bias[colB + nt * 16];

  if (mode <= 1) {
#pragma unroll
    for (int mt = 0; mt < 8; mt++) {
      int rg0 = row0 + wr * 128 + mt * 16 + quad * 4;
#pragma unroll
      for (int nt = 0; nt < 4; nt++) {
#pragma unroll
        for (int r = 0; r < 4; r++) {
          int rg = rg0 + r;
          if (rg < M) {
            float val = (acc[mt][nt][r] + bv4[nt]) * scale;
            size_t off = (size_t)rg * ldc + colB + nt * 16;
            if (mode == 1) ((float*)C)[off] = val;
            else           ((ushort_t*)C)[off] = f2b(val);
          }
        }
      }
    }
  } else {
    int vslot = (mode == 4);
    int head = (by * 256 + wc * 64) >> 6;   // 0..7, one 64-col head per wave
#pragma unroll
    for (int mt = 0; mt < 8; mt++) {
#pragma unroll
      for (int r = 0; r < 4; r++) {
        int rg = row0 + wr * 128 + mt * 16 + quad * 4 + r;
        float v0 = acc[mt][0][r] + bv4[0];
        float v1 = acc[mt][1][r] + bv4[1];
        float v2 = acc[mt][2][r] + bv4[2];
        float v3 = acc[mt][3][r] + bv4[3];
        float am = fmaxf(fmaxf(fabsf(v0), fabsf(v1)), fmaxf(fabsf(v2), fabsf(v3)));
        am = fmaxf(am, __shfl_xor(am, 1));
        am = fmaxf(am, __shfl_xor(am, 2));
        am = fmaxf(am, __shfl_xor(am, 4));
        am = fmaxf(am, __shfl_xor(am, 8));
        am = fmaxf(am, 1e-20f);
        float inv8 = 127.0f / am;
        float sc8 = am * (1.0f / 127.0f);
        if (rg < M) {
          unsigned char* Crow = (unsigned char*)C + (size_t)rg * KVROW;
          // dim d = head*64 + nt*16 + lm -> byte 16*(d>>3) + 8*vslot + (d&7)
          unsigned char* bp = Crow + head * 128 + (lm >> 3) * 16 + 8 * vslot + (lm & 7);
          bp[ 0] = (unsigned char)(signed char)(int)rintf(v0 * inv8);
          bp[32] = (unsigned char)(signed char)(int)rintf(v1 * inv8);
          bp[64] = (unsigned char)(signed char)(int)rintf(v2 * inv8);
          bp[96] = (unsigned char)(signed char)(int)rintf(v3 * inv8);
          if (lm == 0)
            *(float*)(Crow + 1024 + head * 8 + vslot * 4) = sc8;
        }
      }
    }
  }
}

// 1D grid rt*6, XCD-swizzled: the 6 (by,z) blocks of a 256-row panel land in
// one XCD chunk -> A panel fetched once per XCD L2 (r5: FETCH 127->17.6 MB).
// z=0 -> Q plane bf16 (ldc 512, scale 1/8); z=1 -> K int8; z=2 -> V int8.
__global__ __launch_bounds__(512, 2) void k_gemm_qkv(
    const ushort_t* __restrict__ xb, const ushort_t* __restrict__ WT4,
    const float* __restrict__ biasf, ushort_t* Qp, unsigned char* KV8, int M) {
  int swz = xcd_swz(blockIdx.x, gridDim.x);
  int row = swz / 6;
  int sub = swz - row * 6;
  int by = sub & 1, z = sub >> 1;
  const ushort_t* BT = WT4 + (size_t)z * 512 * 512;
  const float* bias = biasf + (size_t)z * 512;
  if (z == 0)
    gemm_body256(xb, BT, bias, Qp, M, 512, 0.125f, row * 256, by, 0);
  else
    gemm_body256(xb, BT, bias, KV8, M, 0, 1.0f, row * 256, by, z == 1 ? 3 : 4);
}

// 1D grid rt*2, same XCD chunking
__global__ __launch_bounds__(512, 2) void k_gemm_out(
    const ushort_t* __restrict__ y, const ushort_t* __restrict__ WT4,
    const float* __restrict__ biasf, void* out, int M,
    const int* __restrict__ flagp) {
  int mode = *flagp;
  int swz = xcd_swz(blockIdx.x, gridDim.x);
  int row = swz >> 1, by = swz & 1;
  gemm_body256(y, WT4 + (size_t)3 * 512 * 512, biasf + 3 * 512, out, M, 512, 1.0f,
               row * 256, by, mode);
}

// ---------------------------------------------------------------------------
// Per-node attention + V aggregation (r11 = r9 structure RESTORED + wasted-
// prefetch skip). One WAVE per node; lane l owns dims [8l,8l+8), head h=l>>3.
// De-chained gather: 64-edge chunk of cols loaded with ONE coalesced load,
// per-edge indices broadcast via readlane (register broadcast, no memory
// dependency) -> depth-4 KV ring genuinely in flight.
// *** Structure constraints (all measured, do not revisit): ***
//   - ring depth HARD-CAPPED at 4 (depth 8 spilled twice: r2 WRITE 388MB,
//     r7 301MB; both ~2.4x slower)
//   - 1 wave/node (r10's 4-wave split: 60->102us; per-node Q-load/quant 4x'd,
//     fill rate DROPPED 3.3->1.9 TB/s, +LDS reduce; overhead >> chain gain)
//   - V stays SIGNED int8 (r8 biased-uint8: VALU -5% but time +11%)
// r11 delta vs r9: invalid ring slots (t >= rem) no longer issue clamped
// KV loads (was ~25% wasted gathers at avg degree 16). The skip branch is
// WAVE-UNIFORM (t, rem lane-invariant). Skipped slots get abv=-1e30 and the
// ring is zero-initialized so never-loaded slots can't inject NaN
// (min(NaN,80)=80 would blow up exp).
// K int8 + Q int8 per (node,head) -> 2x v_dot4_i32_i8. No max-subtraction
// (logits O(+-10), clamp 80). Default launch bounds, ~44 VGPR, NO scratch.
// Writes y bf16 over the Q plane.
// ---------------------------------------------------------------------------
__global__ __launch_bounds__(256) void k_edge(
    ushort_t* Qy, const unsigned char* __restrict__ KV8,
    const void* __restrict__ ab, const float* __restrict__ ABc,
    const int* __restrict__ cols, const int* __restrict__ rp, int Nn,
    const int* __restrict__ flagp) {
  int node = blockIdx.x * 4 + (threadIdx.x >> 6);
  if (node >= Nn) return;
  int lane = threadIdx.x & 63;
  int h8 = lane >> 3;
  const float* abf32 = (*flagp) ? (const float*)ab : ABc;

  uint4 qu = ((const uint4*)(Qy + (size_t)node * 512))[lane];
  float qf[8];
  unpack8(qu, qf);

#if HAS_SDOT
  // quantize Q per (node, head): head = one 8-lane group x 8 dims/lane
  float qa = 0.f;
#pragma unroll
  for (int j = 0; j < 8; j++) qa = fmaxf(qa, fabsf(qf[j]));
  qa = fmaxf(qa, __shfl_xor(qa, 1));
  qa = fmaxf(qa, __shfl_xor(qa, 2));
  qa = fmaxf(qa, __shfl_xor(qa, 4));
  qa = fmaxf(qa, 1e-20f);
  float qs = qa * (1.0f / 127.0f);
  float qinv = 127.0f / qa;
  int qp0 = 0, qp1 = 0;
#pragma unroll
  for (int j = 0; j < 4; j++) qp0 |= (((int)rintf(qf[j] * qinv)) & 0xFF) << (8 * j);
#pragma unroll
  for (int j = 4; j < 8; j++) qp1 |= (((int)rintf(qf[j] * qinv)) & 0xFF) << (8 * (j - 4));
#endif

  int e0 = rp[node], e1 = rp[node + 1];
  int cnt = e1 - e0;

  float s0 = 0.f, s1 = 0.f;
  float acc0[8], acc1[8];
#pragma unroll
  for (int j = 0; j < 8; j++) { acc0[j] = 0.f; acc1[j] = 0.f; }

  uint4 kvb[4];
  float2 scb[4];
  float abv[4];
#pragma unroll
  for (int j = 0; j < 4; j++) {        // zero-init: skipped slots stay benign
    kvb[j].x = 0; kvb[j].y = 0; kvb[j].z = 0; kvb[j].w = 0;
    scb[j].x = 0.f; scb[j].y = 0.f;
    abv[j] = -1e30f;
  }

  // chunked over 64 edges: one coalesced cols load per chunk, readlane bcast
  for (int base = 0; base < cnt; base += 64) {
    int rem = cnt - base; if (rem > 64) rem = 64;
    int li = (lane < rem) ? lane : (rem - 1);
    int myc = cols[e0 + base + li];
    const float* abp = abf32 + (size_t)(e0 + base) * 8 + h8;

    auto pref = [&](int t, int slot) {
      if (t >= rem) {                  // wave-uniform skip: no wasted gather
        abv[slot] = -1e30f;            // exp(-1e30)=0 -> no contribution
        return;
      }
      int c = __builtin_amdgcn_readlane(myc, t);
      const unsigned char* kvrow = KV8 + (size_t)c * KVROW;
      kvb[slot] = *(const uint4*)(kvrow + lane * 16);
      scb[slot] = *(const float2*)(kvrow + 1024 + h8 * 8);
      abv[slot] = abp[t * 8];
    };
    auto consume = [&](int slot, float* acc, float& s) {
#if HAS_SDOT
      int di = __builtin_amdgcn_sdot4(qp0, (int)kvb[slot].x, 0, false);
      di = __builtin_amdgcn_sdot4(qp1, (int)kvb[slot].y, di, false);
      di += __shfl_xor(di, 1);
      di += __shfl_xor(di, 2);
      di += __shfl_xor(di, 4);
      float logit = fminf(fmaf((float)di * qs, scb[slot].x, abv[slot]), 80.f);
#else
      float kf[8];
      uint2 ku; ku.x = kvb[slot].x; ku.y = kvb[slot].y;
      unpack_i8x8(ku, kf);
      float d = 0.f;
#pragma unroll
      for (int j = 0; j < 8; j++) d = fmaf(qf[j], kf[j], d);
      d += __shfl_xor(d, 1);
      d += __shfl_xor(d, 2);
      d += __shfl_xor(d, 4);
      float logit = fminf(fmaf(d, scb[slot].x, abv[slot]), 80.f);
#endif
      float pw = __expf(logit);
      s += pw;
      float pwv = pw * scb[slot].y;
      float vf[8];
      uint2 vu; vu.x = kvb[slot].z; vu.y = kvb[slot].w;
      unpack_i8x8(vu, vf);
#pragma unroll
      for (int j = 0; j < 8; j++) acc[j] = fmaf(pwv, vf[j], acc[j]);
    };

    pref(0, 0); pref(1, 1); pref(2, 2); pref(3, 3);
    int iters = (rem + 3) >> 2;
    for (int it = 0; it < iters; ++it) {
      int nt = it * 4 + 4;
      consume(0, acc0, s0); pref(nt + 0, 0);
      consume(1, acc1, s1); pref(nt + 1, 1);
      consume(2, acc0, s0); pref(nt + 2, 2);
      consume(3, acc1, s1); pref(nt + 3, 3);
    }
  }

  float s = s0 + s1;
  float inv = (cnt > 0 && s > 0.f) ? 1.f / s : 0.f;
  ushort_t hb[8];
#pragma unroll
  for (int j = 0; j < 8; j++) hb[j] = f2b((acc0[j] + acc1[j]) * inv);
  uint4 uh;
  uh.x = (uint32)hb[0] | ((uint32)hb[1] << 16);
  uh.y = (uint32)hb[2] | ((uint32)hb[3] << 16);
  uh.z = (uint32)hb[4] | ((uint32)hb[5] << 16);
  uh.w = (uint32)hb[6] | ((uint32)hb[7] << 16);
  ((uint4*)(Qy + (size_t)node * 512))[lane] = uh;
}

// ---------------------------------------------------------------------------
extern "C" void kernel_launch(void* const* d_in, const int* in_sizes, int n_in,
                              void* d_out, int out_size, void* d_ws, size_t ws_size,
                              hipStream_t stream) {
  const void* x  = d_in[0];
  const int* ei  = (const int*)d_in[1];
  const void* ab = d_in[2];
  const void* Wq = d_in[3];
  const void* bq = d_in[4];
  const void* Wk = d_in[5];
  const void* bk = d_in[6];
  const void* Wv = d_in[7];
  const void* bv = d_in[8];
  const void* Wo = d_in[9];
  const void* bo = d_in[10];

  const int D = 512;
  int M = in_sizes[0] / D;   // 20000 nodes
  int E = in_sizes[1] / 2;   // 320000 edges
  const int* rows = ei;
  const int* cols = ei + E;

  char* p = (char*)d_ws;
  size_t off = 0;
  auto carve = [&](size_t bytes) -> void* {
    off = (off + 255) & ~(size_t)255;
    void* r = p + off;
    off += bytes;
    return r;
  };
  int* flag          = (int*)carve(4);
  ushort_t* WT4      = (ushort_t*)carve((size_t)4 * 512 * 512 * 2);  //  2.00 MB
  float* biasf       = (float*)carve((size_t)4 * 512 * 4);           //  0.01 MB
  ushort_t* xb       = (ushort_t*)carve((size_t)M * 512 * 2);        // 20.48 MB
  ushort_t* Qp       = (ushort_t*)carve((size_t)M * 512 * 2);        // 20.48 MB (y aliases)
  unsigned char* KV8 = (unsigned char*)carve((size_t)M * KVROW);     // 21.76 MB
  int* rp            = (int*)carve((size_t)(M + 1) * 4);             //  0.08 MB

  // ABc: prefer its own carve (lets convab run inside k_prep). Fall back to
  // aliasing xb (then convab must run AFTER k_gemm_qkv, costing one launch).
  int n4 = E * 8 / 4;
  size_t abBytes = (size_t)E * 8 * 4;
  float* ABc;
  int abEarly;
  if (off + 256 + abBytes <= ws_size) {
    ABc = (float*)carve(abBytes);      // 10.24 MB, total ~76 MB
    abEarly = 1;
  } else {
    ABc = (float*)xb;                  // xb dead after k_gemm_qkv
    abEarly = 0;
  }

  int n8 = M * 512 / 8;
  int nCx = (n8 + 255) / 256;
  int nRp = (M + 1 + 255) / 256;
  int nAb = (n4 + 255) / 256;
  int oRp = 1032 + nCx;
  int oAb = oRp + nRp;
  int oEnd = oAb + nAb;

  k_prep<<<oEnd, 256, 0, stream>>>(x, Wq, Wk, Wv, Wo, WT4, bq, bk, bv, bo,
                                   biasf, xb, ab, ABc, rows, rp, flag,
                                   E, M, n8, n4, abEarly, oRp, oAb);

  int rt = (M + 255) / 256;
  k_gemm_qkv<<<rt * 6, 512, 0, stream>>>(xb, WT4, biasf, Qp, KV8, M);
  if (!abEarly)
    k_convab<<<nAb, 256, 0, stream>>>(ab, ABc, n4, flag);
  k_edge<<<(M + 3) / 4, 256, 0, stream>>>(Qp, KV8, ab, ABc, cols, rp, M, flag);
  k_gemm_out<<<rt * 2, 512, 0, stream>>>(Qp, WT4, biasf, d_out, M, flag);
}